// Round 13
// baseline (159.691 us; speedup 1.0000x reference)
//
#include <hip/hip_runtime.h>

typedef __bf16 bf16_t;
typedef bf16_t bf16x8 __attribute__((ext_vector_type(8)));
typedef bf16_t bf16x4 __attribute__((ext_vector_type(4)));
typedef float f32x4 __attribute__((ext_vector_type(4)));

#define M_TOK 32768
#define NWIN 128
#define WIN  256
#define NQ_ELEMS 196608

typedef __attribute__((address_space(3))) void* as3p;
typedef const __attribute__((address_space(1))) void* as1p;

__device__ __forceinline__ void gll16(const void* g, void* l) {
    __builtin_amdgcn_global_load_lds((as1p)g, (as3p)l, 16, 0, 0);
}

__device__ __forceinline__ bf16x8 cvt8(f32x4 a, f32x4 b) {
    bf16x8 o;
    o[0] = (bf16_t)a[0]; o[1] = (bf16_t)a[1]; o[2] = (bf16_t)a[2]; o[3] = (bf16_t)a[3];
    o[4] = (bf16_t)b[0]; o[5] = (bf16_t)b[1]; o[6] = (bf16_t)b[2]; o[7] = (bf16_t)b[3];
    return o;
}

// weights-only fp32->bf16 convert (256 blocks)
__global__ __launch_bounds__(256) void wconv(
    const float* __restrict__ wq, const float* __restrict__ wp,
    bf16_t* __restrict__ wqb, bf16_t* __restrict__ wpb)
{
    int i4 = (blockIdx.x * 256 + threadIdx.x) * 4;
    const float* s; bf16_t* dst; int idx;
    if (i4 < NQ_ELEMS) { s = wq; dst = wqb; idx = i4; }
    else               { s = wp; dst = wpb; idx = i4 - NQ_ELEMS; }
    f32x4 v = *(const f32x4*)(s + idx);
    bf16x4 o;
    o[0] = (bf16_t)v[0]; o[1] = (bf16_t)v[1]; o[2] = (bf16_t)v[2]; o[3] = (bf16_t)v[3];
    *(bf16x4*)(dst + idx) = o;
}

// GEMM1-Q: Q = relu(X @ Wq^T) with FUSED fp32->bf16 convert of X.
// A staged via registers (fp32 load -> cvt -> ds_write); n0==0 blocks also
// write the converted panel to Xb (consumed by gemm1kv after this kernel).
// Swapped MFMA -> vector stores Qg[8][32768][32].
__global__ __launch_bounds__(256) void gemm1_q(
    const float* __restrict__ X,
    const bf16_t* __restrict__ Wb,
    bf16_t* __restrict__ Xb,
    bf16_t* __restrict__ Qg)
{
    __shared__ bf16_t As[2][128][32];
    __shared__ bf16_t Bs[2][128][32];

    const int tid = threadIdx.x;
    const int lane = tid & 63;
    const int wv = tid >> 6;
    const int wm = wv >> 1, wn = wv & 1;
    const int id = blockIdx.x;
    const int m0 = (id >> 1) * 128, n0 = (id & 1) * 128;
    const int r = lane & 15, q = lane >> 4;
    const int srow = lane >> 2;
    const bool wxb = (n0 == 0);

    // staging map: thread -> (row, 8-elem k-chunk)
    const int arow = tid >> 3;            // +p*32
    const int acol = (tid & 7) * 8;       // 0..56

    f32x4 acc[4][4] = {};

    for (int kc = 0; kc < 256; kc += 64) {
#pragma unroll
        for (int p = 0; p < 4; ++p) {
            const int row = p * 32 + arow;
            const float* xp = X + (size_t)(m0 + row) * 256 + kc + acol;
            f32x4 lo = *(const f32x4*)xp;
            f32x4 hi = *(const f32x4*)(xp + 4);
            bf16x8 cv = cvt8(lo, hi);
            *(bf16x8*)&As[acol >> 5][row][acol & 31] = cv;
            if (wxb) *(bf16x8*)&Xb[(size_t)(m0 + row) * 256 + kc + acol] = cv;
        }
#pragma unroll
        for (int p = 0; p < 2; ++p)
#pragma unroll
            for (int g = 0; g < 2; ++g) {
                const int rb = wv * 32 + g * 16;
                gll16(Wb + (size_t)(n0 + rb + srow) * 256 + kc + p * 32 + (lane & 3) * 8,
                      &Bs[p][rb][0]);
            }
        __syncthreads();

#pragma unroll
        for (int kk = 0; kk < 64; kk += 32) {
            const int pA = kk >> 5;
            bf16x8 a[4], b[4];
#pragma unroll
            for (int i = 0; i < 4; ++i)
                a[i] = *(const bf16x8*)&As[pA][wm * 64 + i * 16 + r][q * 8];
#pragma unroll
            for (int j = 0; j < 4; ++j)
                b[j] = *(const bf16x8*)&Bs[pA][wn * 64 + j * 16 + r][q * 8];
#pragma unroll
            for (int i = 0; i < 4; ++i)
#pragma unroll
                for (int j = 0; j < 4; ++j)   // swapped: col->token(r), rows->n
                    acc[i][j] = __builtin_amdgcn_mfma_f32_16x16x32_bf16(b[j], a[i], acc[i][j], 0, 0, 0);
        }
        __syncthreads();
    }

#pragma unroll
    for (int i = 0; i < 4; ++i) {
        const int rowg = m0 + wm * 64 + i * 16 + r;
#pragma unroll
        for (int j = 0; j < 4; ++j) {
            const int nb = n0 + wn * 64 + j * 16 + q * 4;
            const int hq = nb >> 5, d = nb & 31;
            bf16x4 o;
#pragma unroll
            for (int reg = 0; reg < 4; ++reg)
                o[reg] = (bf16_t)fmaxf(acc[i][j][reg], 0.0f);   // relu (q)
            *(bf16x4*)&Qg[((size_t)hq * M_TOK + rowg) * 32 + d] = o;
        }
    }
}

// GEMM1-KV: K/V half (n0>=256), all-bf16, natural MFMA (acc rows = tokens)
// -> vector bf16x4 stores into TRANSPOSED KTg/VTg[8][32][32768].
__global__ __launch_bounds__(256) void gemm1_kv(
    const bf16_t* __restrict__ Xb,
    const bf16_t* __restrict__ Wb,
    bf16_t* __restrict__ KTg,
    bf16_t* __restrict__ VTg)
{
    __shared__ bf16_t As[2][128][32];
    __shared__ bf16_t Bs[2][128][32];

    const int tid = threadIdx.x;
    const int lane = tid & 63;
    const int wv = tid >> 6;
    const int wm = wv >> 1, wn = wv & 1;
    const int id = blockIdx.x;
    const int m0 = (id >> 2) * 128;
    const int n0 = 256 + (id & 3) * 128;
    const int r = lane & 15, q = lane >> 4;
    const int srow = lane >> 2;

    f32x4 acc[4][4] = {};

    for (int kc = 0; kc < 256; kc += 64) {
#pragma unroll
        for (int p = 0; p < 2; ++p)
#pragma unroll
            for (int g = 0; g < 2; ++g) {
                const int rb = wv * 32 + g * 16;
                gll16(Xb + (size_t)(m0 + rb + srow) * 256 + kc + p * 32 + (lane & 3) * 8,
                      &As[p][rb][0]);
                gll16(Wb + (size_t)(n0 + rb + srow) * 256 + kc + p * 32 + (lane & 3) * 8,
                      &Bs[p][rb][0]);
            }
        __syncthreads();

#pragma unroll
        for (int kk = 0; kk < 64; kk += 32) {
            const int pA = kk >> 5;
            bf16x8 a[4], b[4];
#pragma unroll
            for (int i = 0; i < 4; ++i)
                a[i] = *(const bf16x8*)&As[pA][wm * 64 + i * 16 + r][q * 8];
#pragma unroll
            for (int j = 0; j < 4; ++j)
                b[j] = *(const bf16x8*)&Bs[pA][wn * 64 + j * 16 + r][q * 8];
#pragma unroll
            for (int i = 0; i < 4; ++i)
#pragma unroll
                for (int j = 0; j < 4; ++j)   // natural: col->n(r), rows->token
                    acc[i][j] = __builtin_amdgcn_mfma_f32_16x16x32_bf16(a[i], b[j], acc[i][j], 0, 0, 0);
        }
        __syncthreads();
    }

    const bool isK = (n0 < 512);
    bf16_t* base = isK ? KTg : VTg;
#pragma unroll
    for (int i = 0; i < 4; ++i) {
        const int tok0 = m0 + wm * 64 + i * 16 + q * 4;
#pragma unroll
        for (int j = 0; j < 4; ++j) {
            const int nb = n0 + wn * 64 + j * 16 + r;   // channel (lane-varying)
            const int hh = (nb >> 5) & 7;
            const int c  = nb & 31;
            bf16x4 o;
#pragma unroll
            for (int reg = 0; reg < 4; ++reg) {
                float v = acc[i][j][reg];
                if (isK) v = fmaxf(v, 0.0f);            // relu (k)
                o[reg] = (bf16_t)v;
            }
            *(bf16x4*)&base[((size_t)hh * 32 + c) * M_TOK + tok0] = o;
        }
    }
}

// GEMM2: Out = Y @ Wproj^T + b, 64x128 tiles (1024 blocks).
__global__ __launch_bounds__(256) void gemm2_proj(
    const bf16_t* __restrict__ Y,
    const bf16_t* __restrict__ Wb,
    const float* __restrict__ bias,
    float* __restrict__ Out)
{
    __shared__ bf16_t As[2][64][32];
    __shared__ bf16_t Bs[2][128][32];

    const int tid = threadIdx.x;
    const int lane = tid & 63;
    const int wv = tid >> 6;
    const int id = blockIdx.x;
    const int sg = id / 16, wsub = id % 16;
    const int m0 = (sg * 8 + (wsub & 7)) * 64;
    const int n0 = (wsub >> 3) * 128;
    const int r = lane & 15, q = lane >> 4;
    const int srow = lane >> 2;

    f32x4 acc[4][2] = {};

    for (int kc = 0; kc < 256; kc += 64) {
#pragma unroll
        for (int p = 0; p < 2; ++p)
            gll16(Y + (size_t)(m0 + wv * 16 + srow) * 256 + kc + p * 32 + (lane & 3) * 8,
                  &As[p][wv * 16][0]);
#pragma unroll
        for (int p = 0; p < 2; ++p)
#pragma unroll
            for (int g = 0; g < 2; ++g)
                gll16(Wb + (size_t)(n0 + wv * 32 + g * 16 + srow) * 256 + kc + p * 32 + (lane & 3) * 8,
                      &Bs[p][wv * 32 + g * 16][0]);
        __syncthreads();

#pragma unroll
        for (int kk = 0; kk < 64; kk += 32) {
            const int pB = kk >> 5;
            bf16x8 a[4], b[2];
#pragma unroll
            for (int i = 0; i < 4; ++i)
                a[i] = *(const bf16x8*)&As[pB][i * 16 + r][q * 8];
#pragma unroll
            for (int j = 0; j < 2; ++j)
                b[j] = *(const bf16x8*)&Bs[pB][wv * 32 + j * 16 + r][q * 8];
#pragma unroll
            for (int i = 0; i < 4; ++i)
#pragma unroll
                for (int j = 0; j < 2; ++j)
                    acc[i][j] = __builtin_amdgcn_mfma_f32_16x16x32_bf16(b[j], a[i], acc[i][j], 0, 0, 0);
        }
        __syncthreads();
    }

#pragma unroll
    for (int i = 0; i < 4; ++i) {
        const int rowg = m0 + i * 16 + r;
#pragma unroll
        for (int j = 0; j < 2; ++j) {
            const int nb = n0 + wv * 32 + j * 16 + q * 4;
            f32x4 bi = *(const f32x4*)(bias + nb);
            f32x4 o;
#pragma unroll
            for (int reg = 0; reg < 4; ++reg) o[reg] = acc[i][j][reg] + bi[reg];
            *(f32x4*)&Out[(size_t)rowg * 256 + nb] = o;
        }
    }
}

// Fused per-(window,head) linear attention; K/V frags direct from transposed
// global with FULL PREFETCH (16 loads in flight before the MFMA chain).
__global__ __launch_bounds__(256) void kvy_kernel(
    const bf16_t* __restrict__ Qg,    // [8][32768][32]
    const bf16_t* __restrict__ KTg,   // [8][32][32768]
    const bf16_t* __restrict__ VTg,   // [8][32][32768]
    const int* __restrict__ offsets,
    const int* __restrict__ counts,
    bf16_t* __restrict__ Y)           // [32768,256]
{
    const int w = blockIdx.x;
    const int h = blockIdx.y;
    const int is64 = (counts[1] == 0) ? 1 : 0;
    const int off = offsets[w << is64];
    const int tid = threadIdx.x;
    const int lane = tid & 63;
    const int wv = tid >> 6;
    const int r = lane & 15, q = lane >> 4;

    __shared__ __align__(16) bf16_t KVT[32 * 40];  // KVT[d][c]
    __shared__ float sbuf[32];
    __shared__ float zinv[WIN];

    // P1: KV = K^T V + s = K^T 1, all fragment loads prefetched
    {
        const int i = wv >> 1, j = wv & 1;
        bf16x8 ones;
#pragma unroll
        for (int u = 0; u < 8; ++u) ones[u] = (bf16_t)1.0f;
        const bf16_t* kr = KTg + ((size_t)h * 32 + i * 16 + r) * M_TOK + off + q * 8;
        const bf16_t* vr = VTg + ((size_t)h * 32 + j * 16 + r) * M_TOK + off + q * 8;
        bf16x8 kfr[8], vfr[8];
#pragma unroll
        for (int ch = 0; ch < 8; ++ch) {
            kfr[ch] = *(const bf16x8*)(kr + ch * 32);
            vfr[ch] = *(const bf16x8*)(vr + ch * 32);
        }
        f32x4 acc = {}, accs = {};
#pragma unroll
        for (int ch = 0; ch < 8; ++ch) {
            acc  = __builtin_amdgcn_mfma_f32_16x16x32_bf16(kfr[ch], vfr[ch], acc, 0, 0, 0);
            accs = __builtin_amdgcn_mfma_f32_16x16x32_bf16(kfr[ch], ones, accs, 0, 0, 0);
        }
        bf16x4 kv4;
#pragma unroll
        for (int reg = 0; reg < 4; ++reg) kv4[reg] = (bf16_t)acc[reg];
        *(bf16x4*)(&KVT[(j * 16 + r) * 40 + i * 16 + q * 4]) = kv4;
        if (j == 0 && r == 0) {
#pragma unroll
            for (int reg = 0; reg < 4; ++reg)
                sbuf[i * 16 + q * 4 + reg] = accs[reg];
        }
    }
    __syncthreads();

    // P2: zinv[t] = 1/(q[t].s + eps)
    {
        const int t = tid;
        const bf16_t* qp = Qg + ((size_t)h * M_TOK + off + t) * 32;
        float z = 0.f;
#pragma unroll
        for (int u = 0; u < 4; ++u) {
            bf16x8 qq = *(const bf16x8*)(qp + u * 8);
#pragma unroll
            for (int jj = 0; jj < 8; ++jj) z += (float)qq[jj] * sbuf[u * 8 + jj];
        }
        zinv[t] = 1.0f / (z + 1e-3f);
    }
    __syncthreads();

    // P3: y = (Q.KV)*zinv, swapped MFMA (col-field->token, row-field->d)
    {
        bf16x8 b0 = *(const bf16x8*)(&KVT[(r) * 40 + q * 8]);
        bf16x8 b1 = *(const bf16x8*)(&KVT[(16 + r) * 40 + q * 8]);
#pragma unroll
        for (int u = 0; u < 4; ++u) {
            const int mi = wv * 4 + u;
            const bf16_t* ap = Qg + ((size_t)h * M_TOK + off + mi * 16 + r) * 32 + q * 8;
            bf16x8 af = *(const bf16x8*)ap;
            f32x4 acc0 = {}, acc1 = {};
            acc0 = __builtin_amdgcn_mfma_f32_16x16x32_bf16(b0, af, acc0, 0, 0, 0);
            acc1 = __builtin_amdgcn_mfma_f32_16x16x32_bf16(b1, af, acc1, 0, 0, 0);
            const int tkn = mi * 16 + r;
            const float zi = zinv[tkn];
            bf16_t* yp = Y + (size_t)(off + tkn) * 256 + h * 32;
            bf16x4 o0, o1;
#pragma unroll
            for (int reg = 0; reg < 4; ++reg) {
                o0[reg] = (bf16_t)(acc0[reg] * zi);
                o1[reg] = (bf16_t)(acc1[reg] * zi);
            }
            *(bf16x4*)(yp + q * 4) = o0;
            *(bf16x4*)(yp + 16 + q * 4) = o1;
        }
    }
}

extern "C" void kernel_launch(void* const* d_in, const int* in_sizes, int n_in,
                              void* d_out, int out_size, void* d_ws, size_t ws_size,
                              hipStream_t stream) {
    const float* x      = (const float*)d_in[0];
    const float* w_qkv  = (const float*)d_in[1];
    const float* w_proj = (const float*)d_in[2];
    const float* b_proj = (const float*)d_in[3];
    const int*   offs   = (const int*)d_in[4];
    const int*   cnts   = (const int*)d_in[5];

    char* ws = (char*)d_ws;
    bf16_t* Xb  = (bf16_t*)ws;                    // 16777216 B (aliased as Y after gemm1_kv)
    bf16_t* Qg  = (bf16_t*)(ws + 16777216);       // 16777216 B
    bf16_t* KTg = (bf16_t*)(ws + 33554432);       // 16777216 B
    bf16_t* VTg = (bf16_t*)(ws + 50331648);       // 16777216 B
    bf16_t* Wqb = (bf16_t*)(ws + 67108864);       //   393216 B
    bf16_t* Wpb = (bf16_t*)(ws + 67502080);       //   131072 B
    bf16_t* Y   = Xb;                              // Xb dead after gemm1_kv
    float*  out = (float*)d_out;

    // 0) weights fp32->bf16 ((196608+65536)/1024 = 256 blocks)
    wconv<<<256, 256, 0, stream>>>(w_qkv, w_proj, Wqb, Wpb);

    // 1a) Q gemm with fused X convert (n0==0 blocks publish Xb)
    gemm1_q<<<512, 256, 0, stream>>>(x, Wqb, Xb, Qg);

    // 1b) K/V gemm from converted Xb, transposed outputs
    gemm1_kv<<<1024, 256, 0, stream>>>(Xb, Wqb, KTg, VTg);

    // 2+3) fused per-(window,head) KV + normalize
    kvy_kernel<<<dim3(NWIN, 8), 256, 0, stream>>>(Qg, KTg, VTg, offs, cnts, Y);

    // 4) proj gemm, fp32 out
    gemm2_proj<<<1024, 256, 0, stream>>>(Y, Wpb, b_proj, out);
}